// Round 1
// baseline (1030.687 us; speedup 1.0000x reference)
//
#include <hip/hip_runtime.h>
#include <hip/hip_bf16.h>
#include <math.h>

// Problem constants (N, C, H, W) = (4, 256, 64, 64), out_C = 256, FS=3, pad=1, stride=1
#define NB     4
#define CIN    256
#define HH     64
#define WW     64
#define OUTC   256
#define K2     9
#define KTOT   (CIN * K2)          // 2304
#define HWSZ   (HH * WW)           // 4096

// Workspace layout (floats)
#define WS_BT    0                           // Bt  [KTOT][256]  = 589824
#define WS_BT2   589824                      // Bt2 [KTOT][32]   = 73728
#define WS_OM    (589824 + 73728)            // om  [N][27][64][64] = 442368
// total = 1105920 floats = 4.42 MB

// ---------------------------------------------------------------------------
// Kernel 0: weight transposes
//   Bt [kk*256 + oc]  = dcn_w[oc*2304 + kk]           (GEMM B, kk-major)
//   Bt2[kk*32  + oc]  = offset_w[oc*2304 + kk], oc<27 (padded to 32 cols)
// ---------------------------------------------------------------------------
__global__ __launch_bounds__(256) void prep_kernel(
    const float* __restrict__ dcn_w, const float* __restrict__ offw,
    float* __restrict__ Bt, float* __restrict__ Bt2) {
  int idx = blockIdx.x * 256 + threadIdx.x;
  if (idx < KTOT * OUTC) {
    int kk = idx >> 8;
    int oc = idx & 255;
    Bt[idx] = dcn_w[oc * KTOT + kk];
  }
  if (idx < KTOT * 32) {
    int kk = idx >> 5;
    int oc = idx & 31;
    Bt2[idx] = (oc < 27) ? offw[oc * KTOT + kk] : 0.0f;
  }
}

// ---------------------------------------------------------------------------
// Kernel 1: offset conv  om[n][oc][h][w], oc in [0,27)
//   block = 256 threads: lane = w (64), wave q owns oc in [q*8, q*8+8) (pad >26)
//   grid  = N*H = 256 blocks (one per (n,h) row)
//   A-tile (8c x 9tap x 64w) staged in LDS per chunk; weight rows via
//   wave-uniform pointer (readfirstlane) -> scalar loads.
//   Mask channels (oc>=18) get sigmoid applied here.
// ---------------------------------------------------------------------------
__global__ __launch_bounds__(256) void conv_offset_kernel(
    const float* __restrict__ x, const float* __restrict__ Bt2,
    const float* __restrict__ ob, float* __restrict__ om) {
  __shared__ float As[72 * 64];

  int bid  = blockIdx.x;
  int n    = bid >> 6;
  int h    = bid & 63;
  int tid  = threadIdx.x;
  int lane = tid & 63;
  int q    = __builtin_amdgcn_readfirstlane(tid >> 6);

  const float* xn = x + n * (CIN * HWSZ);

  float acc[8];
#pragma unroll
  for (int j = 0; j < 8; ++j) acc[j] = 0.0f;

  for (int c0 = 0; c0 < CIN; c0 += 8) {
    __syncthreads();
    // stage A: 8c * 9tap * 64w = 4608 values
    for (int v = tid; v < 4608; v += 256) {
      int w  = v & 63;
      int t  = (v >> 6) % 9;
      int cc = v / 576;
      int ky = t / 3, kx = t % 3;
      int y  = h + ky - 1;
      int xx = w + kx - 1;
      float val = 0.0f;
      if ((unsigned)y < 64u && (unsigned)xx < 64u)
        val = xn[(c0 + cc) * HWSZ + y * 64 + xx];
      As[(cc * 9 + t) * 64 + w] = val;
    }
    __syncthreads();

    const float* bbase = Bt2 + (c0 * 9) * 32 + q * 8;
#pragma unroll 4
    for (int kk = 0; kk < 72; ++kk) {
      float a = As[kk * 64 + lane];
      const float* br = bbase + kk * 32;
#pragma unroll
      for (int j = 0; j < 8; ++j) acc[j] = fmaf(a, br[j], acc[j]);
    }
  }

  int oc0 = q * 8;
#pragma unroll
  for (int j = 0; j < 8; ++j) {
    int oc = oc0 + j;
    if (oc < 27) {
      float val = acc[j] + ob[oc];
      if (oc >= 18) val = 1.0f / (1.0f + expf(-val));  // sigmoid for mask
      om[(n * 27 + oc) * HWSZ + h * 64 + lane] = val;
    }
  }
}

// ---------------------------------------------------------------------------
// Kernel 2: deformable sampling + main contraction as GEMM
//   block: M = 32 spatial (half row), N = 256 oc, K = 2304
//   grid : N*H*2 = 512 blocks (2 blocks/CU)
//   thread tile: 4m x 8n; A from LDS (b128), B from global (L2-resident)
// ---------------------------------------------------------------------------
__global__ __launch_bounds__(256) void dcn_main_kernel(
    const float* __restrict__ x, const float* __restrict__ om,
    const float* __restrict__ Bt, float* __restrict__ out) {
  __shared__ float  As[72 * 32];
  __shared__ int    sY[288];
  __shared__ int    sX[288];
  __shared__ float4 sW[288];

  int bid = blockIdx.x;
  int n   = bid >> 7;
  int rem = bid & 127;
  int h   = rem >> 1;
  int w0  = (rem & 1) * 32;

  int tid   = threadIdx.x;
  int m_idx = tid & 7;    // 8 m-groups * 4 m = 32
  int n_idx = tid >> 3;   // 32 n-groups * 8 n = 256

  const float* xn  = x + n * (CIN * HWSZ);
  const float* omn = om + n * (27 * HWSZ);

  // ---- bilinear params for 9 taps x 32 w positions ----
  for (int v = tid; v < 288; v += 256) {
    int w  = v & 31;
    int t  = v >> 5;  // 0..8
    int ky = t / 3, kx = t % 3;
    int wg = w0 + w;
    int sp = h * 64 + wg;
    float offy = omn[(2 * t) * HWSZ + sp];
    float offx = omn[(2 * t + 1) * HWSZ + sp];
    float mv   = omn[(18 + t) * HWSZ + sp];
    float him  = (float)(h - 1 + ky) + offy;
    float wim  = (float)(wg - 1 + kx) + offx;
    float y0f = floorf(him), x0f = floorf(wim);
    float lh = him - y0f, lw = wim - x0f;
    int y0 = (int)y0f, x0 = (int)x0f;
    bool vy0 = (y0 >= 0) && (y0 < HH);
    bool vy1 = (y0 + 1 >= 0) && (y0 + 1 < HH);
    bool vx0 = (x0 >= 0) && (x0 < WW);
    bool vx1 = (x0 + 1 >= 0) && (x0 + 1 < WW);
    float hh_ = 1.0f - lh, hw_ = 1.0f - lw;
    float4 wt;
    wt.x = (vy0 && vx0) ? hh_ * hw_ * mv : 0.0f;
    wt.y = (vy0 && vx1) ? hh_ * lw  * mv : 0.0f;
    wt.z = (vy1 && vx0) ? lh  * hw_ * mv : 0.0f;
    wt.w = (vy1 && vx1) ? lh  * lw  * mv : 0.0f;
    sY[v] = y0;
    sX[v] = x0;
    sW[v] = wt;
  }

  float acc[8][4];
#pragma unroll
  for (int ni = 0; ni < 8; ++ni)
#pragma unroll
    for (int mi = 0; mi < 4; ++mi) acc[ni][mi] = 0.0f;

  for (int c0 = 0; c0 < CIN; c0 += 8) {
    __syncthreads();  // first iter: params ready; later: protect As reuse
    // ---- stage A: 8c x 9tap x 32w = 2304 sampled values ----
    for (int v = tid; v < 2304; v += 256) {
      int w  = v & 31;
      int t  = (v >> 5) % 9;
      int cc = v / 288;
      int p  = t * 32 + w;
      int y0 = sY[p], x0 = sX[p];
      float4 wt = sW[p];
      int y0c = min(max(y0, 0), HH - 1);
      int y1c = min(max(y0 + 1, 0), HH - 1);
      int x0c = min(max(x0, 0), WW - 1);
      int x1c = min(max(x0 + 1, 0), WW - 1);
      const float* xb = xn + (c0 + cc) * HWSZ;
      float val = wt.x * xb[y0c * 64 + x0c] + wt.y * xb[y0c * 64 + x1c] +
                  wt.z * xb[y1c * 64 + x0c] + wt.w * xb[y1c * 64 + x1c];
      As[(cc * 9 + t) * 32 + w] = val;
    }
    __syncthreads();

    const float* bbase = Bt + (c0 * 9) * 256 + n_idx * 8;
#pragma unroll 4
    for (int kk = 0; kk < 72; ++kk) {
      const float4 av = *reinterpret_cast<const float4*>(&As[kk * 32 + (m_idx << 2)]);
      const float4* br4 = reinterpret_cast<const float4*>(bbase + kk * 256);
      float4 b0 = br4[0];
      float4 b1 = br4[1];
      float am[4] = {av.x, av.y, av.z, av.w};
      float bv[8] = {b0.x, b0.y, b0.z, b0.w, b1.x, b1.y, b1.z, b1.w};
#pragma unroll
      for (int ni = 0; ni < 8; ++ni)
#pragma unroll
        for (int mi = 0; mi < 4; ++mi)
          acc[ni][mi] = fmaf(am[mi], bv[ni], acc[ni][mi]);
    }
  }

  // ---- epilogue: out[n][oc][h][w0 + m_idx*4 .. +3] ----
#pragma unroll
  for (int ni = 0; ni < 8; ++ni) {
    int oc = n_idx * 8 + ni;
    float4 v = make_float4(acc[ni][0], acc[ni][1], acc[ni][2], acc[ni][3]);
    *reinterpret_cast<float4*>(
        &out[(n * OUTC + oc) * HWSZ + h * 64 + w0 + (m_idx << 2)]) = v;
  }
}

// ---------------------------------------------------------------------------
extern "C" void kernel_launch(void* const* d_in, const int* in_sizes, int n_in,
                              void* d_out, int out_size, void* d_ws, size_t ws_size,
                              hipStream_t stream) {
  const float* x     = (const float*)d_in[0];
  const float* offw  = (const float*)d_in[1];
  const float* ob    = (const float*)d_in[2];
  const float* dcn_w = (const float*)d_in[3];
  float* out = (float*)d_out;
  float* ws  = (float*)d_ws;

  float* Bt  = ws + WS_BT;
  float* Bt2 = ws + WS_BT2;
  float* omb = ws + WS_OM;

  // 1) weight transposes
  prep_kernel<<<(KTOT * OUTC + 255) / 256, 256, 0, stream>>>(dcn_w, offw, Bt, Bt2);
  // 2) offset conv (+sigmoid on mask channels)
  conv_offset_kernel<<<NB * HH, 256, 0, stream>>>(x, Bt2, ob, omb);
  // 3) deformable sampling + main contraction
  dcn_main_kernel<<<NB * HH * 2, 256, 0, stream>>>(x, omb, Bt, out);
}

// Round 2
// 311.148 us; speedup vs baseline: 3.3125x; 3.3125x over previous
//
#include <hip/hip_runtime.h>
#include <hip/hip_bf16.h>
#include <math.h>

// Problem constants (N, C, H, W) = (4, 256, 64, 64), out_C = 256, FS=3, pad=1, stride=1
#define NB     4
#define CIN    256
#define HH     64
#define WW     64
#define OUTC   256
#define K2     9
#define KTOT   2304                // CIN * K2
#define HWSZ   4096                // HH * WW
#define NSTEPS 72                  // KTOT / 32

// K-dimension ordering: kk' = tap*256 + c  (tap-major) so each 32-wide K-step
// lives inside a single tap -> no div/mod in the sampling hot loop.

typedef __attribute__((ext_vector_type(4))) float  floatx4;
typedef __attribute__((ext_vector_type(8))) short  short8;
typedef __attribute__((ext_vector_type(4))) short  short4v;

__device__ __forceinline__ unsigned short f2bf(float f) {
  union { float f; unsigned u; } v; v.f = f;
  unsigned r = v.u + 0x7FFF + ((v.u >> 16) & 1);   // round-to-nearest-even
  return (unsigned short)(r >> 16);
}

// Workspace layout (bytes):
//   Bw  : [256 oc][2304 kk'] bf16  = 1,179,648 B   (main GEMM B, kk'-major per row)
//   B2w : [32 oc ][2304 kk'] bf16  =   147,456 B   (offset conv B, oc>=27 zero)
//   om  : [4][27][64][64] fp32     = 1,769,472 B
#define WS_BW_OFF   0
#define WS_B2W_OFF  (KTOT * OUTC * 2)
#define WS_OM_OFF   (WS_B2W_OFF + KTOT * 32 * 2)

// ---------------------------------------------------------------------------
// Kernel 0: weight conversion/transpose to bf16, kk' = t*256 + c ordering.
// One block per oc (256 blocks).
// ---------------------------------------------------------------------------
__global__ __launch_bounds__(256) void prep_kernel(
    const float* __restrict__ dcn_w, const float* __restrict__ offw,
    unsigned short* __restrict__ Bw, unsigned short* __restrict__ B2w) {
  int oc = blockIdx.x;
  for (int k = threadIdx.x; k < KTOT; k += 256) {
    int t = k >> 8, c = k & 255;
    Bw[oc * KTOT + k] = f2bf(dcn_w[oc * KTOT + c * 9 + t]);
    if (oc < 32)
      B2w[oc * KTOT + k] = (oc < 27) ? f2bf(offw[oc * KTOT + c * 9 + t])
                                     : (unsigned short)0;
  }
}

// ---------------------------------------------------------------------------
// Kernel 1: offset conv via MFMA.  GEMM: M=64 (one spatial row), N=32 (27 oc
// padded), K=2304.  Grid = N*H = 256 blocks, 256 threads (4 waves).
// Wave q owns m-tile q (16 w positions) x both n-tiles -> 2 MFMA/step.
// Bias + sigmoid (mask channels) fused in epilogue.
// ---------------------------------------------------------------------------
__global__ __launch_bounds__(256) void conv_offset_kernel(
    const float* __restrict__ x, const unsigned short* __restrict__ B2w,
    const float* __restrict__ ob, float* __restrict__ om) {
  __shared__ unsigned short A_lds[64 * 40];   // [w][c], row stride 40 (pad)
  __shared__ unsigned short B_lds[32 * 40];   // [oc][c]

  int bid  = blockIdx.x;
  int n    = bid >> 6;
  int h    = bid & 63;
  int tid  = threadIdx.x;
  int lane = tid & 63;
  int q    = tid >> 6;

  const float* xn = x + n * (CIN * HWSZ);

  floatx4 acc0 = {0.f, 0.f, 0.f, 0.f};
  floatx4 acc1 = {0.f, 0.f, 0.f, 0.f};

  int w    = tid & 63;       // A-stage: spatial w
  int cg   = tid >> 6;       // A-stage: c-group (0..3), 8 c each
  int ocb  = tid >> 3;       // B-stage: oc row (0..31)
  int part = tid & 7;        // B-stage: 4-short chunk

  for (int s = 0; s < NSTEPS; ++s) {
    int t  = s >> 3;
    int c0 = (s & 7) << 5;
    int dy = t / 3 - 1, dx = t % 3 - 1;
    __syncthreads();
    // ---- stage A: x[n][c][h+dy][w+dx] (zero-pad OOB), 8 c per thread ----
    {
      int y  = h + dy;
      int xx = w + dx;
      bool inb = ((unsigned)y < 64u) && ((unsigned)xx < 64u);
      const float* xb = xn + (c0 + cg * 8) * HWSZ + y * 64 + xx;
      short8 pk;
#pragma unroll
      for (int j = 0; j < 8; ++j) {
        float v = inb ? xb[j * HWSZ] : 0.0f;
        pk[j] = (short)f2bf(v);
      }
      *(short8*)&A_lds[w * 40 + cg * 8] = pk;
    }
    // ---- stage B: 32x32 bf16 ----
    {
      const unsigned short* bp = B2w + ocb * KTOT + (t << 8) + c0 + part * 4;
      *(short4v*)&B_lds[ocb * 40 + part * 4] = *(const short4v*)bp;
    }
    __syncthreads();
    int fr = (lane >> 4) * 8;
    short8 af  = *(short8*)&A_lds[(q * 16 + (lane & 15)) * 40 + fr];
    short8 bf0 = *(short8*)&B_lds[((lane & 15)) * 40 + fr];
    short8 bf1 = *(short8*)&B_lds[(16 + (lane & 15)) * 40 + fr];
    acc0 = __builtin_amdgcn_mfma_f32_16x16x32_bf16(af, bf0, acc0, 0, 0, 0);
    acc1 = __builtin_amdgcn_mfma_f32_16x16x32_bf16(af, bf1, acc1, 0, 0, 0);
  }

  // ---- epilogue: D row = m (w), col = oc; bias + sigmoid for oc>=18 ----
  int g = lane >> 4;
#pragma unroll
  for (int nt = 0; nt < 2; ++nt) {
    floatx4 a = nt ? acc1 : acc0;
    int oc = nt * 16 + (lane & 15);
    if (oc < 27) {
      float bias = ob[oc];
#pragma unroll
      for (int r = 0; r < 4; ++r) {
        int wm = q * 16 + g * 4 + r;
        float val = a[r] + bias;
        if (oc >= 18) val = 1.0f / (1.0f + __expf(-val));
        om[((n * 27 + oc) << 12) + h * 64 + wm] = val;
      }
    }
  }
}

// ---------------------------------------------------------------------------
// Kernel 2: deformable sampling + main contraction via MFMA.
// GEMM per block: M=32 spatial (half row), N=256 oc, K=2304 (72 steps of 32).
// Grid = 512 blocks (2/CU), 256 threads (4 waves).
// Wave q: n in [q*64, q*64+64) -> 2 m-tiles x 4 n-tiles = 8 MFMA/step.
// ---------------------------------------------------------------------------
__global__ __launch_bounds__(256) void dcn_main_kernel(
    const float* __restrict__ x, const float* __restrict__ om,
    const unsigned short* __restrict__ Bw, float* __restrict__ out) {
  __shared__ unsigned short A_lds[32 * 40];    // [m][c], stride 40
  __shared__ unsigned short B_lds[256 * 40];   // [oc][c], stride 40
  __shared__ int    sY[288];                   // [tap][m]
  __shared__ int    sX[288];
  __shared__ float4 sW[288];                   // mask-premultiplied corner wts

  int bid = blockIdx.x;
  int n   = bid >> 7;
  int rem = bid & 127;
  int h   = rem >> 1;
  int w0  = (rem & 1) << 5;

  int tid  = threadIdx.x;
  int lane = tid & 63;
  int q    = tid >> 6;

  const float* xn  = x + n * (CIN * HWSZ);
  const float* omn = om + n * (27 * HWSZ);

  // ---- bilinear params: 9 taps x 32 m ----
  for (int v = tid; v < 288; v += 256) {
    int m = v & 31, t = v >> 5;
    int ky = t / 3, kx = t % 3;
    int wg = w0 + m;
    int sp = h * 64 + wg;
    float offy = omn[(2 * t) * HWSZ + sp];
    float offx = omn[(2 * t + 1) * HWSZ + sp];
    float mv   = omn[(18 + t) * HWSZ + sp];
    float him  = (float)(h - 1 + ky) + offy;
    float wim  = (float)(wg - 1 + kx) + offx;
    float y0f = floorf(him), x0f = floorf(wim);
    float lh = him - y0f, lw = wim - x0f;
    int y0 = (int)y0f, x0i = (int)x0f;
    bool vy0 = (y0 >= 0) && (y0 < HH);
    bool vy1 = (y0 + 1 >= 0) && (y0 + 1 < HH);
    bool vx0 = (x0i >= 0) && (x0i < WW);
    bool vx1 = (x0i + 1 >= 0) && (x0i + 1 < WW);
    float hh_ = 1.0f - lh, hw_ = 1.0f - lw;
    float4 wt;
    wt.x = (vy0 && vx0) ? hh_ * hw_ * mv : 0.0f;
    wt.y = (vy0 && vx1) ? hh_ * lw  * mv : 0.0f;
    wt.z = (vy1 && vx0) ? lh  * hw_ * mv : 0.0f;
    wt.w = (vy1 && vx1) ? lh  * lw  * mv : 0.0f;
    sY[v] = y0; sX[v] = x0i; sW[v] = wt;
  }

  floatx4 acc[2][4];
#pragma unroll
  for (int mi = 0; mi < 2; ++mi)
#pragma unroll
    for (int nj = 0; nj < 4; ++nj) acc[mi][nj] = (floatx4){0.f, 0.f, 0.f, 0.f};

  int m  = tid & 31;    // A-stage: spatial m
  int cg = tid >> 5;    // A-stage: c-group (0..7), 4 c each
  int n0 = q * 64;

  for (int s = 0; s < NSTEPS; ++s) {
    int t  = s >> 3;
    int c0 = (s & 7) << 5;
    __syncthreads();
    // ---- stage A: bilinear sample 32m x 32c, 4 c per thread ----
    {
      int p = t * 32 + m;
      int y0 = sY[p], x0i = sX[p];
      float4 wt = sW[p];
      int y0c = min(max(y0, 0), 63),     y1c = min(max(y0 + 1, 0), 63);
      int x0c = min(max(x0i, 0), 63),    x1c = min(max(x0i + 1, 0), 63);
      int i00 = y0c * 64 + x0c, i01 = y0c * 64 + x1c;
      int i10 = y1c * 64 + x0c, i11 = y1c * 64 + x1c;
      const float* xb = xn + (c0 + cg * 4) * HWSZ;
      short4v pk;
#pragma unroll
      for (int j = 0; j < 4; ++j) {
        const float* xc = xb + j * HWSZ;
        float v = wt.x * xc[i00] + wt.y * xc[i01] +
                  wt.z * xc[i10] + wt.w * xc[i11];
        pk[j] = (short)f2bf(v);
      }
      *(short4v*)&A_lds[m * 40 + cg * 4] = pk;
    }
    // ---- stage B: 256 oc x 32 c bf16 (64 B per thread-row) ----
    {
      const short8* bp = (const short8*)(Bw + tid * KTOT + (t << 8) + c0);
      short8 b0 = bp[0], b1 = bp[1], b2 = bp[2], b3 = bp[3];
      short8* dst = (short8*)&B_lds[tid * 40];
      dst[0] = b0; dst[1] = b1; dst[2] = b2; dst[3] = b3;
    }
    __syncthreads();
    // ---- fragments + 8 MFMA ----
    int fr = (lane >> 4) * 8;
    short8 a0 = *(short8*)&A_lds[((lane & 15)) * 40 + fr];
    short8 a1 = *(short8*)&A_lds[(16 + (lane & 15)) * 40 + fr];
#pragma unroll
    for (int nj = 0; nj < 4; ++nj) {
      short8 bfp = *(short8*)&B_lds[(n0 + nj * 16 + (lane & 15)) * 40 + fr];
      acc[0][nj] = __builtin_amdgcn_mfma_f32_16x16x32_bf16(a0, bfp, acc[0][nj], 0, 0, 0);
      acc[1][nj] = __builtin_amdgcn_mfma_f32_16x16x32_bf16(a1, bfp, acc[1][nj], 0, 0, 0);
    }
  }

  // ---- epilogue: pack r=0..3 (consecutive m) into float4 stores ----
  int g = lane >> 4;
#pragma unroll
  for (int mi = 0; mi < 2; ++mi) {
    int wm = w0 + mi * 16 + g * 4;
#pragma unroll
    for (int nj = 0; nj < 4; ++nj) {
      int oc = n0 + nj * 16 + (lane & 15);
      float4 vv = make_float4(acc[mi][nj][0], acc[mi][nj][1],
                              acc[mi][nj][2], acc[mi][nj][3]);
      *(float4*)&out[((n * OUTC + oc) << 12) + h * 64 + wm] = vv;
    }
  }
}

// ---------------------------------------------------------------------------
extern "C" void kernel_launch(void* const* d_in, const int* in_sizes, int n_in,
                              void* d_out, int out_size, void* d_ws, size_t ws_size,
                              hipStream_t stream) {
  const float* x     = (const float*)d_in[0];
  const float* offw  = (const float*)d_in[1];
  const float* ob    = (const float*)d_in[2];
  const float* dcn_w = (const float*)d_in[3];
  float* out = (float*)d_out;

  unsigned short* Bw  = (unsigned short*)((char*)d_ws + WS_BW_OFF);
  unsigned short* B2w = (unsigned short*)((char*)d_ws + WS_B2W_OFF);
  float*          omb = (float*)((char*)d_ws + WS_OM_OFF);

  prep_kernel<<<256, 256, 0, stream>>>(dcn_w, offw, Bw, B2w);
  conv_offset_kernel<<<NB * HH, 256, 0, stream>>>(x, B2w, ob, omb);
  dcn_main_kernel<<<NB * HH * 2, 256, 0, stream>>>(x, omb, Bw, out);
}

// Round 3
// 258.674 us; speedup vs baseline: 3.9845x; 1.2029x over previous
//
#include <hip/hip_runtime.h>
#include <hip/hip_bf16.h>
#include <math.h>

// Problem constants (N, C, H, W) = (4, 256, 64, 64), out_C = 256, FS=3, pad=1, stride=1
#define NB     4
#define CIN    256
#define HH     64
#define WW     64
#define OUTC   256
#define K2     9
#define KTOT   2304                // CIN * K2
#define HWSZ   4096                // HH * WW
#define NSTEPS 72                  // KTOT / 32
#define MTOT   16384               // NB * HWSZ

// K ordering everywhere: k' = tap*256 + c (tap-major).

typedef __attribute__((ext_vector_type(4))) float  floatx4;
typedef __attribute__((ext_vector_type(8))) short  short8;
typedef __attribute__((ext_vector_type(4))) short  short4v;
typedef __attribute__((ext_vector_type(4))) int    intx4;

__device__ __forceinline__ unsigned short f2bf(float f) {
  union { float f; unsigned u; } v; v.f = f;
  unsigned r = v.u + 0x7FFF + ((v.u >> 16) & 1);   // round-to-nearest-even
  return (unsigned short)(r >> 16);
}

__device__ __forceinline__ void load_lds16(const void* g, void* l) {
  __builtin_amdgcn_global_load_lds(
      (const __attribute__((address_space(1))) unsigned int*)g,
      (__attribute__((address_space(3))) unsigned int*)l, 16, 0, 0);
}

// Workspace layout (bytes):
//   Bw  : [256 oc][2304 k'] bf16 = 1,179,648
//   B2w : [32 oc ][2304 k'] bf16 =   147,456
//   om  : [4][27][64][64] fp32   = 1,769,472   (RAW conv output, no bias/sigmoid)
//   A   : [m][2304 k'] bf16      = 18,874,368 per image (chunked)
#define WS_BW_OFF   0
#define WS_B2W_OFF  (KTOT * OUTC * 2)
#define WS_OM_OFF   (WS_B2W_OFF + KTOT * 32 * 2)
#define WS_A_OFF    (WS_OM_OFF + NB * 27 * HWSZ * 4)

// ---------------------------------------------------------------------------
// Kernel 0: weight conversion/transpose to bf16, k' = t*256 + c ordering.
// ---------------------------------------------------------------------------
__global__ __launch_bounds__(256) void prep_kernel(
    const float* __restrict__ dcn_w, const float* __restrict__ offw,
    unsigned short* __restrict__ Bw, unsigned short* __restrict__ B2w) {
  int oc = blockIdx.x;
  for (int k = threadIdx.x; k < KTOT; k += 256) {
    int t = k >> 8, c = k & 255;
    Bw[oc * KTOT + k] = f2bf(dcn_w[oc * KTOT + c * 9 + t]);
    if (oc < 32)
      B2w[oc * KTOT + k] = (oc < 27) ? f2bf(offw[oc * KTOT + c * 9 + t])
                                     : (unsigned short)0;
  }
}

// ---------------------------------------------------------------------------
// Kernel 1: offset conv, streaming register-fragment MFMA (no LDS, no barrier).
// Grid = MTOT/32 = 512 blocks, 256 thr (4 waves). Wave: 1 m-tile(16) x 1 n-tile.
// Writes RAW om (bias + sigmoid applied in sample_kernel).
// ---------------------------------------------------------------------------
__global__ __launch_bounds__(256) void conv_offset_stream(
    const float* __restrict__ x, const unsigned short* __restrict__ B2w,
    float* __restrict__ om) {
  int tid = threadIdx.x, lane = tid & 63, q = tid >> 6;
  int qm = q & 1, qn = q >> 1;
  int quad = lane >> 4, l15 = lane & 15;
  int mbase = blockIdx.x * 32 + qm * 16;
  int mrow  = mbase + l15;
  int w = mrow & 63, h = (mrow >> 6) & 63, img = mrow >> 12;
  const float* xn = x + img * (CIN * HWSZ);
  int ocr = qn * 16 + l15;
  const unsigned short* bbase = B2w + ocr * KTOT + quad * 8;

  floatx4 acc = {0.f, 0.f, 0.f, 0.f};
  for (int s = 0; s < NSTEPS; ++s) {
    int t  = s >> 3;
    int cb = ((s & 7) << 5) + (quad << 3);
    int dy = t / 3 - 1, dx = t % 3 - 1;
    int y = h + dy, xx = w + dx;
    bool inb = ((unsigned)y < 64u) && ((unsigned)xx < 64u);
    const float* xp = xn + cb * HWSZ + y * 64 + xx;
    short8 af;
#pragma unroll
    for (int j = 0; j < 8; ++j) {
      float v = inb ? xp[j * HWSZ] : 0.0f;
      af[j] = (short)f2bf(v);
    }
    short8 bf = *(const short8*)(bbase + s * 32);
    acc = __builtin_amdgcn_mfma_f32_16x16x32_bf16(af, bf, acc, 0, 0, 0);
  }
  if (ocr < 27) {
    int m0 = mbase + quad * 4;
    int img2 = m0 >> 12, hw = m0 & 4095;
    float4 vv = make_float4(acc[0], acc[1], acc[2], acc[3]);
    *(float4*)&om[(img2 * 27 + ocr) * HWSZ + hw] = vv;
  }
}

// ---------------------------------------------------------------------------
// Kernel 2: deformable bilinear sampling -> A[m][k'] bf16 (im2col-like).
// Grid = nimg*64*4 blocks: (img-local, h, c-quarter). 256 thr.
// Params (corner idx + mask-premultiplied weights, bias+sigmoid) in LDS.
// Thread: slot=tid&3 (c-chunk), w=tid>>2. Stores short8 -> 64 B segments.
// ---------------------------------------------------------------------------
__global__ __launch_bounds__(256) void sample_kernel(
    const float* __restrict__ x, const float* __restrict__ om,
    const float* __restrict__ ob, unsigned short* __restrict__ A,
    int imgbase) {
  __shared__ intx4  sIdx[576];
  __shared__ float4 sWt[576];

  int bid = blockIdx.x;
  int cq = bid & 3, h = (bid >> 2) & 63, il = bid >> 8;
  int img = imgbase + il;
  const float* xn  = x + img * (CIN * HWSZ);
  const float* omn = om + img * (27 * HWSZ);
  int tid = threadIdx.x;

  for (int v = tid; v < 576; v += 256) {
    int t = v >> 6, w = v & 63;
    int ky = t / 3, kx = t % 3;
    int sp = h * 64 + w;
    float offy = omn[(2 * t) * HWSZ + sp] + ob[2 * t];
    float offx = omn[(2 * t + 1) * HWSZ + sp] + ob[2 * t + 1];
    float mraw = omn[(18 + t) * HWSZ + sp] + ob[18 + t];
    float mv   = 1.0f / (1.0f + __expf(-mraw));
    float him  = (float)(h - 1 + ky) + offy;
    float wim  = (float)(w - 1 + kx) + offx;
    float y0f = floorf(him), x0f = floorf(wim);
    float lh = him - y0f, lw = wim - x0f;
    int y0 = (int)y0f, x0i = (int)x0f;
    bool vy0 = (y0 >= 0) && (y0 < HH);
    bool vy1 = (y0 + 1 >= 0) && (y0 + 1 < HH);
    bool vx0 = (x0i >= 0) && (x0i < WW);
    bool vx1 = (x0i + 1 >= 0) && (x0i + 1 < WW);
    float hh_ = 1.0f - lh, hw_ = 1.0f - lw;
    float4 wt;
    wt.x = (vy0 && vx0) ? hh_ * hw_ * mv : 0.0f;
    wt.y = (vy0 && vx1) ? hh_ * lw  * mv : 0.0f;
    wt.z = (vy1 && vx0) ? lh  * hw_ * mv : 0.0f;
    wt.w = (vy1 && vx1) ? lh  * lw  * mv : 0.0f;
    int y0c = min(max(y0, 0), 63), y1c = min(max(y0 + 1, 0), 63);
    int x0c = min(max(x0i, 0), 63), x1c = min(max(x0i + 1, 0), 63);
    intx4 ii = {y0c * 64 + x0c, y0c * 64 + x1c, y1c * 64 + x0c, y1c * 64 + x1c};
    sIdx[v] = ii;
    sWt[v]  = wt;
  }
  __syncthreads();

  int slot = tid & 3, w = tid >> 2;
  size_t mrow = (size_t)(il * HWSZ + h * 64 + w) * KTOT;
  for (int t = 0; t < 9; ++t) {
    intx4  ii = sIdx[t * 64 + w];
    float4 wt = sWt[t * 64 + w];
#pragma unroll
    for (int cc = 0; cc < 2; ++cc) {
      int c = cq * 64 + slot * 8 + cc * 32;
      const float* xp = xn + c * HWSZ;
      short8 pk;
#pragma unroll
      for (int j = 0; j < 8; ++j) {
        const float* p = xp + j * HWSZ;
        float v = wt.x * p[ii.x] + wt.y * p[ii.y] +
                  wt.z * p[ii.z] + wt.w * p[ii.w];
        pk[j] = (short)f2bf(v);
      }
      *(short8*)&A[mrow + t * 256 + c] = pk;
    }
  }
}

// ---------------------------------------------------------------------------
// Kernel 3: GEMM  out[m][oc] = A[m][k] * Bw[oc][k],  M=chunk, N=256, K=2304.
// BM=64, BN=128, BK=64; 256 thr (4 waves), wave-tile 32x64 (2m x 4n 16x16).
// global_load_lds width-16 staging with XOR-chunk swizzle (no bank conflicts).
// ---------------------------------------------------------------------------
__global__ __launch_bounds__(256) void gemm_kernel(
    const unsigned short* __restrict__ A, const unsigned short* __restrict__ Bw,
    float* __restrict__ out) {
  __shared__ unsigned short Ald[64 * 64];    // 8 KB : 64 rows x 128 B
  __shared__ unsigned short Bld[128 * 64];   // 16 KB: 128 rows x 128 B

  int bid = blockIdx.x;
  int bm = bid >> 1, bn = bid & 1;
  int M0 = bm * 64, N0 = bn * 128;
  int tid = threadIdx.x, lane = tid & 63, q = tid >> 6;
  int qm = q >> 1, qn = q & 1;
  int quad = lane >> 4, l15 = lane & 15;
  int srow = lane >> 3, schk = lane & 7;

  floatx4 acc[2][4];
#pragma unroll
  for (int mi = 0; mi < 2; ++mi)
#pragma unroll
    for (int nj = 0; nj < 4; ++nj) acc[mi][nj] = (floatx4){0.f, 0.f, 0.f, 0.f};

  for (int s = 0; s < 36; ++s) {
    int k0 = s * 64;
    __syncthreads();
    // stage A: wave q -> rows [q*16, q*16+16)
#pragma unroll
    for (int it = 0; it < 2; ++it) {
      int rb = q * 16 + it * 8;
      int r  = rb + srow;
      const unsigned short* g =
          A + (size_t)(M0 + r) * KTOT + k0 + ((schk ^ (r & 7)) << 3);
      load_lds16(g, &Ald[rb * 64]);
    }
    // stage B: wave q -> rows [q*32, q*32+32)
#pragma unroll
    for (int it = 0; it < 4; ++it) {
      int rb = q * 32 + it * 8;
      int r  = rb + srow;
      const unsigned short* g =
          Bw + (size_t)(N0 + r) * KTOT + k0 + ((schk ^ (r & 7)) << 3);
      load_lds16(g, &Bld[rb * 64]);
    }
    __syncthreads();
#pragma unroll
    for (int ks = 0; ks < 2; ++ks) {
      int cbase = ks * 4 + quad;
      short8 a[2], b[4];
#pragma unroll
      for (int mi = 0; mi < 2; ++mi) {
        int r = qm * 32 + mi * 16 + l15;
        a[mi] = *(short8*)&Ald[r * 64 + ((cbase ^ (r & 7)) << 3)];
      }
#pragma unroll
      for (int nj = 0; nj < 4; ++nj) {
        int r = qn * 64 + nj * 16 + l15;
        b[nj] = *(short8*)&Bld[r * 64 + ((cbase ^ (r & 7)) << 3)];
      }
#pragma unroll
      for (int mi = 0; mi < 2; ++mi)
#pragma unroll
        for (int nj = 0; nj < 4; ++nj)
          acc[mi][nj] = __builtin_amdgcn_mfma_f32_16x16x32_bf16(
              a[mi], b[nj], acc[mi][nj], 0, 0, 0);
    }
  }

  // epilogue: D col = oc, rows = m (quad*4 + r)
#pragma unroll
  for (int mi = 0; mi < 2; ++mi) {
    int m0 = M0 + qm * 32 + mi * 16 + quad * 4;
    int img = m0 >> 12, hw = m0 & 4095;
#pragma unroll
    for (int nj = 0; nj < 4; ++nj) {
      int oc = N0 + qn * 64 + nj * 16 + l15;
      float4 vv = make_float4(acc[mi][nj][0], acc[mi][nj][1],
                              acc[mi][nj][2], acc[mi][nj][3]);
      *(float4*)&out[((size_t)img * OUTC + oc) * HWSZ + hw] = vv;
    }
  }
}

// ===========================================================================
// FALLBACK PATH (round-2 fused kernels) — used only if ws_size is too small
// to materialize even one image of A.
// ===========================================================================
__global__ __launch_bounds__(256) void conv_offset_kernel(
    const float* __restrict__ x, const unsigned short* __restrict__ B2w,
    const float* __restrict__ ob, float* __restrict__ om) {
  __shared__ unsigned short A_lds[64 * 40];
  __shared__ unsigned short B_lds[32 * 40];
  int bid = blockIdx.x;
  int n = bid >> 6, h = bid & 63;
  int tid = threadIdx.x, lane = tid & 63, q = tid >> 6;
  const float* xn = x + n * (CIN * HWSZ);
  floatx4 acc0 = {0.f, 0.f, 0.f, 0.f}, acc1 = {0.f, 0.f, 0.f, 0.f};
  int w = tid & 63, cg = tid >> 6, ocb = tid >> 3, part = tid & 7;
  for (int s = 0; s < NSTEPS; ++s) {
    int t = s >> 3, c0 = (s & 7) << 5;
    int dy = t / 3 - 1, dx = t % 3 - 1;
    __syncthreads();
    {
      int y = h + dy, xx = w + dx;
      bool inb = ((unsigned)y < 64u) && ((unsigned)xx < 64u);
      const float* xb = xn + (c0 + cg * 8) * HWSZ + y * 64 + xx;
      short8 pk;
#pragma unroll
      for (int j = 0; j < 8; ++j) { float v = inb ? xb[j * HWSZ] : 0.0f; pk[j] = (short)f2bf(v); }
      *(short8*)&A_lds[w * 40 + cg * 8] = pk;
    }
    { const unsigned short* bp = B2w + ocb * KTOT + (t << 8) + c0 + part * 4;
      *(short4v*)&B_lds[ocb * 40 + part * 4] = *(const short4v*)bp; }
    __syncthreads();
    int fr = (lane >> 4) * 8;
    short8 af  = *(short8*)&A_lds[(q * 16 + (lane & 15)) * 40 + fr];
    short8 bf0 = *(short8*)&B_lds[((lane & 15)) * 40 + fr];
    short8 bf1 = *(short8*)&B_lds[(16 + (lane & 15)) * 40 + fr];
    acc0 = __builtin_amdgcn_mfma_f32_16x16x32_bf16(af, bf0, acc0, 0, 0, 0);
    acc1 = __builtin_amdgcn_mfma_f32_16x16x32_bf16(af, bf1, acc1, 0, 0, 0);
  }
  int g = lane >> 4;
#pragma unroll
  for (int nt = 0; nt < 2; ++nt) {
    floatx4 a = nt ? acc1 : acc0;
    int oc = nt * 16 + (lane & 15);
    if (oc < 27) {
      float bias = ob[oc];
#pragma unroll
      for (int r = 0; r < 4; ++r) {
        int wm = q * 16 + g * 4 + r;
        float val = a[r] + bias;
        if (oc >= 18) val = 1.0f / (1.0f + __expf(-val));
        om[((n * 27 + oc) << 12) + h * 64 + wm] = val;
      }
    }
  }
}

__global__ __launch_bounds__(256) void dcn_main_kernel(
    const float* __restrict__ x, const float* __restrict__ om,
    const unsigned short* __restrict__ Bw, float* __restrict__ out) {
  __shared__ unsigned short A_lds[32 * 40];
  __shared__ unsigned short B_lds[256 * 40];
  __shared__ int    sY[288];
  __shared__ int    sX[288];
  __shared__ float4 sW[288];
  int bid = blockIdx.x;
  int n = bid >> 7, rem = bid & 127, h = rem >> 1, w0 = (rem & 1) << 5;
  int tid = threadIdx.x, lane = tid & 63, q = tid >> 6;
  const float* xn  = x + n * (CIN * HWSZ);
  const float* omn = om + n * (27 * HWSZ);
  for (int v = tid; v < 288; v += 256) {
    int m = v & 31, t = v >> 5;
    int ky = t / 3, kx = t % 3;
    int wg = w0 + m, sp = h * 64 + wg;
    float offy = omn[(2 * t) * HWSZ + sp];
    float offx = omn[(2 * t + 1) * HWSZ + sp];
    float mv   = omn[(18 + t) * HWSZ + sp];
    float him = (float)(h - 1 + ky) + offy;
    float wim = (float)(wg - 1 + kx) + offx;
    float y0f = floorf(him), x0f = floorf(wim);
    float lh = him - y0f, lw = wim - x0f;
    int y0 = (int)y0f, x0i = (int)x0f;
    bool vy0 = (y0 >= 0) && (y0 < HH), vy1 = (y0 + 1 >= 0) && (y0 + 1 < HH);
    bool vx0 = (x0i >= 0) && (x0i < WW), vx1 = (x0i + 1 >= 0) && (x0i + 1 < WW);
    float hh_ = 1.0f - lh, hw_ = 1.0f - lw;
    float4 wt;
    wt.x = (vy0 && vx0) ? hh_ * hw_ * mv : 0.0f;
    wt.y = (vy0 && vx1) ? hh_ * lw  * mv : 0.0f;
    wt.z = (vy1 && vx0) ? lh  * hw_ * mv : 0.0f;
    wt.w = (vy1 && vx1) ? lh  * lw  * mv : 0.0f;
    sY[v] = y0; sX[v] = x0i; sW[v] = wt;
  }
  floatx4 acc[2][4];
#pragma unroll
  for (int mi = 0; mi < 2; ++mi)
#pragma unroll
    for (int nj = 0; nj < 4; ++nj) acc[mi][nj] = (floatx4){0.f, 0.f, 0.f, 0.f};
  int m = tid & 31, cg = tid >> 5, n0 = q * 64;
  for (int s = 0; s < NSTEPS; ++s) {
    int t = s >> 3, c0 = (s & 7) << 5;
    __syncthreads();
    {
      int p = t * 32 + m;
      int y0 = sY[p], x0i = sX[p];
      float4 wt = sW[p];
      int y0c = min(max(y0, 0), 63), y1c = min(max(y0 + 1, 0), 63);
      int x0c = min(max(x0i, 0), 63), x1c = min(max(x0i + 1, 0), 63);
      int i00 = y0c * 64 + x0c, i01 = y0c * 64 + x1c;
      int i10 = y1c * 64 + x0c, i11 = y1c * 64 + x1c;
      const float* xb = xn + (c0 + cg * 4) * HWSZ;
      short4v pk;
#pragma unroll
      for (int j = 0; j < 4; ++j) {
        const float* xc = xb + j * HWSZ;
        float v = wt.x * xc[i00] + wt.y * xc[i01] + wt.z * xc[i10] + wt.w * xc[i11];
        pk[j] = (short)f2bf(v);
      }
      *(short4v*)&A_lds[m * 40 + cg * 4] = pk;
    }
    {
      const short8* bp = (const short8*)(Bw + tid * KTOT + (t << 8) + c0);
      short8 b0 = bp[0], b1 = bp[1], b2 = bp[2], b3 = bp[3];
      short8* dst = (short8*)&B_lds[tid * 40];
      dst[0] = b0; dst[1] = b1; dst[2] = b2; dst[3] = b3;
    }
    __syncthreads();
    int fr = (lane >> 4) * 8;
    short8 a0 = *(short8*)&A_lds[((lane & 15)) * 40 + fr];
    short8 a1 = *(short8*)&A_lds[(16 + (lane & 15)) * 40 + fr];
#pragma unroll
    for (int nj = 0; nj < 4; ++nj) {
      short8 bfp = *(short8*)&B_lds[(n0 + nj * 16 + (lane & 15)) * 40 + fr];
      acc[0][nj] = __builtin_amdgcn_mfma_f32_16x16x32_bf16(a0, bfp, acc[0][nj], 0, 0, 0);
      acc[1][nj] = __builtin_amdgcn_mfma_f32_16x16x32_bf16(a1, bfp, acc[1][nj], 0, 0, 0);
    }
  }
  int g = lane >> 4;
#pragma unroll
  for (int mi = 0; mi < 2; ++mi) {
    int wm = w0 + mi * 16 + g * 4;
#pragma unroll
    for (int nj = 0; nj < 4; ++nj) {
      int oc = n0 + nj * 16 + (lane & 15);
      float4 vv = make_float4(acc[mi][nj][0], acc[mi][nj][1],
                              acc[mi][nj][2], acc[mi][nj][3]);
      *(float4*)&out[((n * OUTC + oc) << 12) + h * 64 + wm] = vv;
    }
  }
}

// ---------------------------------------------------------------------------
extern "C" void kernel_launch(void* const* d_in, const int* in_sizes, int n_in,
                              void* d_out, int out_size, void* d_ws, size_t ws_size,
                              hipStream_t stream) {
  const float* x     = (const float*)d_in[0];
  const float* offw  = (const float*)d_in[1];
  const float* ob    = (const float*)d_in[2];
  const float* dcn_w = (const float*)d_in[3];
  float* out = (float*)d_out;

  unsigned short* Bw  = (unsigned short*)((char*)d_ws + WS_BW_OFF);
  unsigned short* B2w = (unsigned short*)((char*)d_ws + WS_B2W_OFF);
  float*          omb = (float*)((char*)d_ws + WS_OM_OFF);
  unsigned short* Abuf = (unsigned short*)((char*)d_ws + WS_A_OFF);

  const size_t perimg = (size_t)HWSZ * KTOT * 2;   // 18.87 MB per image of A
  const size_t head   = (size_t)WS_A_OFF;

  int imgs_per_chunk = 0;
  if (ws_size >= head + 4 * perimg)      imgs_per_chunk = 4;
  else if (ws_size >= head + 2 * perimg) imgs_per_chunk = 2;
  else if (ws_size >= head + 1 * perimg) imgs_per_chunk = 1;

  prep_kernel<<<256, 256, 0, stream>>>(dcn_w, offw, Bw, B2w);

  if (imgs_per_chunk > 0) {
    conv_offset_stream<<<MTOT / 32, 256, 0, stream>>>(x, B2w, omb);
    for (int i0 = 0; i0 < NB; i0 += imgs_per_chunk) {
      int ni = imgs_per_chunk;
      if (i0 + ni > NB) ni = NB - i0;
      sample_kernel<<<ni * 64 * 4, 256, 0, stream>>>(x, omb, ob, Abuf, i0);
      gemm_kernel<<<(ni * HWSZ / 64) * 2, 256, 0, stream>>>(
          Abuf, Bw, out + (size_t)i0 * OUTC * HWSZ);
    }
  } else {
    // ws too small to materialize A: round-2 fused fallback
    conv_offset_kernel<<<NB * HH, 256, 0, stream>>>(x, B2w, ob, omb);
    dcn_main_kernel<<<NB * HH * 2, 256, 0, stream>>>(x, omb, Bw, out);
  }
}

// Round 4
// 180.736 us; speedup vs baseline: 5.7027x; 1.4312x over previous
//
#include <hip/hip_runtime.h>
#include <hip/hip_bf16.h>
#include <math.h>

// Problem constants (N, C, H, W) = (4, 256, 64, 64), out_C = 256, FS=3, pad=1, stride=1
#define NB     4
#define CIN    256
#define HH     64
#define WW     64
#define OUTC   256
#define K2     9
#define KTOT   2304                // CIN * K2
#define HWSZ   4096                // HH * WW
#define NSTEPS 72                  // KTOT / 32
#define MTOT   16384               // NB * HWSZ

// K ordering everywhere: k' = tap*256 + c (tap-major).

typedef __attribute__((ext_vector_type(4))) float  floatx4;
typedef __attribute__((ext_vector_type(8))) short  short8;
typedef __attribute__((ext_vector_type(4))) short  short4v;
typedef __attribute__((ext_vector_type(4))) int    intx4;

__device__ __forceinline__ unsigned short f2bf(float f) {
  union { float f; unsigned u; } v; v.f = f;
  unsigned r = v.u + 0x7FFF + ((v.u >> 16) & 1);   // round-to-nearest-even
  return (unsigned short)(r >> 16);
}
__device__ __forceinline__ float b2f(unsigned short s) {
  union { unsigned u; float f; } v; v.u = ((unsigned)s) << 16;
  return v.f;
}

__device__ __forceinline__ void load_lds16(const void* g, void* l) {
  __builtin_amdgcn_global_load_lds(
      (const __attribute__((address_space(1))) unsigned int*)g,
      (__attribute__((address_space(3))) unsigned int*)l, 16, 0, 0);
}

// Workspace layout (bytes):
//   Bw  : [256 oc][2304 k'] bf16 = 1,179,648
//   B2w : [32 oc ][2304 k'] bf16 =   147,456
//   om  : [4][27][64][64] fp32   = 1,769,472   (RAW conv out, no bias/sigmoid)
//   xt  : [4][64][64][256] bf16  = 8,388,608   (channel-last transposed x)
//   A   : [m][2304 k'] bf16      = 18,874,368 per image (chunked)
#define WS_BW_OFF   0
#define WS_B2W_OFF  (KTOT * OUTC * 2)
#define WS_OM_OFF   (WS_B2W_OFF + KTOT * 32 * 2)
#define WS_XT_OFF   (WS_OM_OFF + NB * 27 * HWSZ * 4)
#define WS_A_OFF    (WS_XT_OFF + NB * HWSZ * CIN * 2)

// ---------------------------------------------------------------------------
// Kernel 0: weight conversion/transpose to bf16, k' = t*256 + c ordering.
// ---------------------------------------------------------------------------
__global__ __launch_bounds__(256) void prep_kernel(
    const float* __restrict__ dcn_w, const float* __restrict__ offw,
    unsigned short* __restrict__ Bw, unsigned short* __restrict__ B2w) {
  int oc = blockIdx.x;
  for (int k = threadIdx.x; k < KTOT; k += 256) {
    int t = k >> 8, c = k & 255;
    Bw[oc * KTOT + k] = f2bf(dcn_w[oc * KTOT + c * 9 + t]);
    if (oc < 32)
      B2w[oc * KTOT + k] = (oc < 27) ? f2bf(offw[oc * KTOT + c * 9 + t])
                                     : (unsigned short)0;
  }
}

// ---------------------------------------------------------------------------
// Kernel 0b: x [img][c][h][w] fp32 -> xt [img][h][w][c] bf16 via LDS tile.
// Block = (img, h), grid 256.
// ---------------------------------------------------------------------------
__global__ __launch_bounds__(256) void xpose_kernel(
    const float* __restrict__ x, unsigned short* __restrict__ xt) {
  __shared__ unsigned short T[64 * 266];   // [w][c], pad 266 (odd dw stride)
  int img = blockIdx.x >> 6, h = blockIdx.x & 63;
  const float* xp = x + (size_t)img * CIN * HWSZ + h * 64;
  int tid = threadIdx.x;
  int w = tid & 63, cq = tid >> 6;
  for (int cb = 0; cb < 256; cb += 4) {
    int c = cb + cq;
    T[w * 266 + c] = f2bf(xp[(size_t)c * HWSZ + w]);   // lanes=w: coalesced
  }
  __syncthreads();
  int w2 = tid >> 2, cg = (tid & 3) << 6;
  unsigned short* o = xt + ((size_t)(img * 64 + h) * 64 + w2) * 256 + cg;
#pragma unroll
  for (int i = 0; i < 64; i += 8) {
    short8 v = *(short8*)&T[w2 * 266 + cg + i];
    *(short8*)(o + i) = v;                              // coalesced 512B rows
  }
}

// ---------------------------------------------------------------------------
// Kernel 1: offset conv, streaming register-fragment MFMA (no LDS, no barrier).
// Grid = MTOT/32 = 512 blocks, 256 thr. A-fragments are single 16B loads
// from channel-last xt. Writes RAW om.
// ---------------------------------------------------------------------------
__global__ __launch_bounds__(256) void conv_offset_stream(
    const unsigned short* __restrict__ xt, const unsigned short* __restrict__ B2w,
    float* __restrict__ om) {
  int tid = threadIdx.x, lane = tid & 63, q = tid >> 6;
  int qm = q & 1, qn = q >> 1;
  int quad = lane >> 4, l15 = lane & 15;
  int mbase = blockIdx.x * 32 + qm * 16;
  int mrow  = mbase + l15;
  int w = mrow & 63, h = (mrow >> 6) & 63, img = mrow >> 12;
  const unsigned short* xn = xt + (size_t)img * HWSZ * 256;
  int ocr = qn * 16 + l15;
  const unsigned short* bbase = B2w + ocr * KTOT + quad * 8;

  floatx4 acc = {0.f, 0.f, 0.f, 0.f};
  for (int s = 0; s < NSTEPS; ++s) {
    int t  = s >> 3;
    int cb = ((s & 7) << 5) + (quad << 3);
    int dy = t / 3 - 1, dx = t % 3 - 1;
    int y = h + dy, xx = w + dx;
    bool inb = ((unsigned)y < 64u) && ((unsigned)xx < 64u);
    short8 af = {0, 0, 0, 0, 0, 0, 0, 0};
    if (inb) af = *(const short8*)(xn + ((size_t)(y * 64 + xx)) * 256 + cb);
    short8 bf = *(const short8*)(bbase + s * 32);
    acc = __builtin_amdgcn_mfma_f32_16x16x32_bf16(af, bf, acc, 0, 0, 0);
  }
  if (ocr < 27) {
    int m0 = mbase + quad * 4;
    int img2 = m0 >> 12, hw = m0 & 4095;
    float4 vv = make_float4(acc[0], acc[1], acc[2], acc[3]);
    *(float4*)&om[(img2 * 27 + ocr) * HWSZ + hw] = vv;
  }
}

// ---------------------------------------------------------------------------
// Kernel 2: deformable bilinear sampling -> A[m][k'] bf16, from channel-last
// xt. Block = (img-local, h, half-row): grid ni*128. Per wave-iteration
// (t, m): 4 fully-coalesced 8B corner loads cover all 256 c; 8B store.
// Params (corner short-offsets + mask-premult weights) in LDS.
// ---------------------------------------------------------------------------
__global__ __launch_bounds__(256) void sample_kernel(
    const unsigned short* __restrict__ xt, const float* __restrict__ om,
    const float* __restrict__ ob, unsigned short* __restrict__ A,
    int imgbase) {
  __shared__ intx4  sOff[288];    // corner offsets in SHORT units
  __shared__ float4 sWt[288];

  int bid = blockIdx.x;
  int half = bid & 1, h = (bid >> 1) & 63, il = bid >> 7;
  int img = imgbase + il;
  int w0 = half << 5;
  const unsigned short* xb = xt + (size_t)img * HWSZ * 256;
  const float* omn = om + img * (27 * HWSZ);
  int tid = threadIdx.x;

  for (int v = tid; v < 288; v += 256) {
    int m = v & 31, t = v >> 5;
    int ky = t / 3, kx = t % 3;
    int wg = w0 + m;
    int sp = h * 64 + wg;
    float offy = omn[(2 * t) * HWSZ + sp] + ob[2 * t];
    float offx = omn[(2 * t + 1) * HWSZ + sp] + ob[2 * t + 1];
    float mraw = omn[(18 + t) * HWSZ + sp] + ob[18 + t];
    float mv   = 1.0f / (1.0f + __expf(-mraw));
    float him  = (float)(h - 1 + ky) + offy;
    float wim  = (float)(wg - 1 + kx) + offx;
    float y0f = floorf(him), x0f = floorf(wim);
    float lh = him - y0f, lw = wim - x0f;
    int y0 = (int)y0f, x0i = (int)x0f;
    bool vy0 = (y0 >= 0) && (y0 < HH);
    bool vy1 = (y0 + 1 >= 0) && (y0 + 1 < HH);
    bool vx0 = (x0i >= 0) && (x0i < WW);
    bool vx1 = (x0i + 1 >= 0) && (x0i + 1 < WW);
    float hh_ = 1.0f - lh, hw_ = 1.0f - lw;
    float4 wt;
    wt.x = (vy0 && vx0) ? hh_ * hw_ * mv : 0.0f;
    wt.y = (vy0 && vx1) ? hh_ * lw  * mv : 0.0f;
    wt.z = (vy1 && vx0) ? lh  * hw_ * mv : 0.0f;
    wt.w = (vy1 && vx1) ? lh  * lw  * mv : 0.0f;
    int y0c = min(max(y0, 0), 63), y1c = min(max(y0 + 1, 0), 63);
    int x0c = min(max(x0i, 0), 63), x1c = min(max(x0i + 1, 0), 63);
    intx4 ii = {(y0c * 64 + x0c) << 8, (y0c * 64 + x1c) << 8,
                (y1c * 64 + x0c) << 8, (y1c * 64 + x1c) << 8};
    sOff[v] = ii;
    sWt[v]  = wt;
  }
  __syncthreads();

  int lane = tid & 63, wv = tid >> 6;
  size_t rowbase = (size_t)(il * HWSZ + h * 64 + w0) * KTOT;
  int cl = lane << 2;   // this lane's 4 channels

  for (int it = wv; it < 288; it += 4) {
    int m = it & 31, t = it >> 5;
    intx4  off = sOff[it];    // wave-uniform
    float4 wt  = sWt[it];
    short4v c0 = *(const short4v*)(xb + off.x + cl);
    short4v c1 = *(const short4v*)(xb + off.y + cl);
    short4v c2 = *(const short4v*)(xb + off.z + cl);
    short4v c3 = *(const short4v*)(xb + off.w + cl);
    short4v pk;
#pragma unroll
    for (int j = 0; j < 4; ++j) {
      float v = wt.x * b2f((unsigned short)c0[j]) +
                wt.y * b2f((unsigned short)c1[j]) +
                wt.z * b2f((unsigned short)c2[j]) +
                wt.w * b2f((unsigned short)c3[j]);
      pk[j] = (short)f2bf(v);
    }
    *(short4v*)&A[rowbase + (size_t)m * KTOT + t * 256 + cl] = pk;
  }
}

// ---------------------------------------------------------------------------
// Kernel 3: GEMM  out[m][oc] = A[m][k] * Bw[oc][k],  M=chunk, N=256, K=2304.
// BM=64, BN=128, BK=64; 256 thr (4 waves), wave-tile 32x64 (2m x 4n 16x16).
// global_load_lds width-16 staging with XOR-chunk swizzle.
// ---------------------------------------------------------------------------
__global__ __launch_bounds__(256) void gemm_kernel(
    const unsigned short* __restrict__ A, const unsigned short* __restrict__ Bw,
    float* __restrict__ out) {
  __shared__ unsigned short Ald[64 * 64];    // 8 KB
  __shared__ unsigned short Bld[128 * 64];   // 16 KB

  int bid = blockIdx.x;
  int bm = bid >> 1, bn = bid & 1;
  int M0 = bm * 64, N0 = bn * 128;
  int tid = threadIdx.x, lane = tid & 63, q = tid >> 6;
  int qm = q >> 1, qn = q & 1;
  int quad = lane >> 4, l15 = lane & 15;
  int srow = lane >> 3, schk = lane & 7;

  floatx4 acc[2][4];
#pragma unroll
  for (int mi = 0; mi < 2; ++mi)
#pragma unroll
    for (int nj = 0; nj < 4; ++nj) acc[mi][nj] = (floatx4){0.f, 0.f, 0.f, 0.f};

  for (int s = 0; s < 36; ++s) {
    int k0 = s * 64;
    __syncthreads();
#pragma unroll
    for (int it = 0; it < 2; ++it) {
      int rb = q * 16 + it * 8;
      int r  = rb + srow;
      const unsigned short* g =
          A + (size_t)(M0 + r) * KTOT + k0 + ((schk ^ (r & 7)) << 3);
      load_lds16(g, &Ald[rb * 64]);
    }
#pragma unroll
    for (int it = 0; it < 4; ++it) {
      int rb = q * 32 + it * 8;
      int r  = rb + srow;
      const unsigned short* g =
          Bw + (size_t)(N0 + r) * KTOT + k0 + ((schk ^ (r & 7)) << 3);
      load_lds16(g, &Bld[rb * 64]);
    }
    __syncthreads();
#pragma unroll
    for (int ks = 0; ks < 2; ++ks) {
      int cbase = ks * 4 + quad;
      short8 a[2], b[4];
#pragma unroll
      for (int mi = 0; mi < 2; ++mi) {
        int r = qm * 32 + mi * 16 + l15;
        a[mi] = *(short8*)&Ald[r * 64 + ((cbase ^ (r & 7)) << 3)];
      }
#pragma unroll
      for (int nj = 0; nj < 4; ++nj) {
        int r = qn * 64 + nj * 16 + l15;
        b[nj] = *(short8*)&Bld[r * 64 + ((cbase ^ (r & 7)) << 3)];
      }
#pragma unroll
      for (int mi = 0; mi < 2; ++mi)
#pragma unroll
        for (int nj = 0; nj < 4; ++nj)
          acc[mi][nj] = __builtin_amdgcn_mfma_f32_16x16x32_bf16(
              a[mi], b[nj], acc[mi][nj], 0, 0, 0);
    }
  }

#pragma unroll
  for (int mi = 0; mi < 2; ++mi) {
    int m0 = M0 + qm * 32 + mi * 16 + quad * 4;
    int img = m0 >> 12, hw = m0 & 4095;
#pragma unroll
    for (int nj = 0; nj < 4; ++nj) {
      int oc = N0 + qn * 64 + nj * 16 + l15;
      float4 vv = make_float4(acc[mi][nj][0], acc[mi][nj][1],
                              acc[mi][nj][2], acc[mi][nj][3]);
      *(float4*)&out[((size_t)img * OUTC + oc) * HWSZ + hw] = vv;
    }
  }
}

// ===========================================================================
// FALLBACK PATH (round-2 fused kernels) — only if ws is too small.
// ===========================================================================
__global__ __launch_bounds__(256) void conv_offset_kernel(
    const float* __restrict__ x, const unsigned short* __restrict__ B2w,
    const float* __restrict__ ob, float* __restrict__ om) {
  __shared__ unsigned short A_lds[64 * 40];
  __shared__ unsigned short B_lds[32 * 40];
  int bid = blockIdx.x;
  int n = bid >> 6, h = bid & 63;
  int tid = threadIdx.x, lane = tid & 63, q = tid >> 6;
  const float* xn = x + n * (CIN * HWSZ);
  floatx4 acc0 = {0.f, 0.f, 0.f, 0.f}, acc1 = {0.f, 0.f, 0.f, 0.f};
  int w = tid & 63, cg = tid >> 6, ocb = tid >> 3, part = tid & 7;
  for (int s = 0; s < NSTEPS; ++s) {
    int t = s >> 3, c0 = (s & 7) << 5;
    int dy = t / 3 - 1, dx = t % 3 - 1;
    __syncthreads();
    {
      int y = h + dy, xx = w + dx;
      bool inb = ((unsigned)y < 64u) && ((unsigned)xx < 64u);
      const float* xb = xn + (c0 + cg * 8) * HWSZ + y * 64 + xx;
      short8 pk;
#pragma unroll
      for (int j = 0; j < 8; ++j) { float v = inb ? xb[j * HWSZ] : 0.0f; pk[j] = (short)f2bf(v); }
      *(short8*)&A_lds[w * 40 + cg * 8] = pk;
    }
    { const unsigned short* bp = B2w + ocb * KTOT + (t << 8) + c0 + part * 4;
      *(short4v*)&B_lds[ocb * 40 + part * 4] = *(const short4v*)bp; }
    __syncthreads();
    int fr = (lane >> 4) * 8;
    short8 af  = *(short8*)&A_lds[(q * 16 + (lane & 15)) * 40 + fr];
    short8 bf0 = *(short8*)&B_lds[((lane & 15)) * 40 + fr];
    short8 bf1 = *(short8*)&B_lds[(16 + (lane & 15)) * 40 + fr];
    acc0 = __builtin_amdgcn_mfma_f32_16x16x32_bf16(af, bf0, acc0, 0, 0, 0);
    acc1 = __builtin_amdgcn_mfma_f32_16x16x32_bf16(af, bf1, acc1, 0, 0, 0);
  }
  int g = lane >> 4;
#pragma unroll
  for (int nt = 0; nt < 2; ++nt) {
    floatx4 a = nt ? acc1 : acc0;
    int oc = nt * 16 + (lane & 15);
    if (oc < 27) {
      float bias = ob[oc];
#pragma unroll
      for (int r = 0; r < 4; ++r) {
        int wm = q * 16 + g * 4 + r;
        float val = a[r] + bias;
        if (oc >= 18) val = 1.0f / (1.0f + __expf(-val));
        om[((n * 27 + oc) << 12) + h * 64 + wm] = val;
      }
    }
  }
}

__global__ __launch_bounds__(256) void dcn_main_kernel(
    const float* __restrict__ x, const float* __restrict__ om,
    const unsigned short* __restrict__ Bw, float* __restrict__ out) {
  __shared__ unsigned short A_lds[32 * 40];
  __shared__ unsigned short B_lds[256 * 40];
  __shared__ int    sY[288];
  __shared__ int    sX[288];
  __shared__ float4 sW[288];
  int bid = blockIdx.x;
  int n = bid >> 7, rem = bid & 127, h = rem >> 1, w0 = (rem & 1) << 5;
  int tid = threadIdx.x, lane = tid & 63, q = tid >> 6;
  const float* xn  = x + n * (CIN * HWSZ);
  const float* omn = om + n * (27 * HWSZ);
  for (int v = tid; v < 288; v += 256) {
    int m = v & 31, t = v >> 5;
    int ky = t / 3, kx = t % 3;
    int wg = w0 + m, sp = h * 64 + wg;
    float offy = omn[(2 * t) * HWSZ + sp];
    float offx = omn[(2 * t + 1) * HWSZ + sp];
    float mv   = omn[(18 + t) * HWSZ + sp];
    float him = (float)(h - 1 + ky) + offy;
    float wim = (float)(wg - 1 + kx) + offx;
    float y0f = floorf(him), x0f = floorf(wim);
    float lh = him - y0f, lw = wim - x0f;
    int y0 = (int)y0f, x0i = (int)x0f;
    bool vy0 = (y0 >= 0) && (y0 < HH), vy1 = (y0 + 1 >= 0) && (y0 + 1 < HH);
    bool vx0 = (x0i >= 0) && (x0i < WW), vx1 = (x0i + 1 >= 0) && (x0i + 1 < WW);
    float hh_ = 1.0f - lh, hw_ = 1.0f - lw;
    float4 wt;
    wt.x = (vy0 && vx0) ? hh_ * hw_ * mv : 0.0f;
    wt.y = (vy0 && vx1) ? hh_ * lw  * mv : 0.0f;
    wt.z = (vy1 && vx0) ? lh  * hw_ * mv : 0.0f;
    wt.w = (vy1 && vx1) ? lh  * lw  * mv : 0.0f;
    sY[v] = y0; sX[v] = x0i; sW[v] = wt;
  }
  floatx4 acc[2][4];
#pragma unroll
  for (int mi = 0; mi < 2; ++mi)
#pragma unroll
    for (int nj = 0; nj < 4; ++nj) acc[mi][nj] = (floatx4){0.f, 0.f, 0.f, 0.f};
  int m = tid & 31, cg = tid >> 5, n0 = q * 64;
  for (int s = 0; s < NSTEPS; ++s) {
    int t = s >> 3, c0 = (s & 7) << 5;
    __syncthreads();
    {
      int p = t * 32 + m;
      int y0 = sY[p], x0i = sX[p];
      float4 wt = sW[p];
      int y0c = min(max(y0, 0), 63), y1c = min(max(y0 + 1, 0), 63);
      int x0c = min(max(x0i, 0), 63), x1c = min(max(x0i + 1, 0), 63);
      int i00 = y0c * 64 + x0c, i01 = y0c * 64 + x1c;
      int i10 = y1c * 64 + x0c, i11 = y1c * 64 + x1c;
      const float* xb = xn + (c0 + cg * 4) * HWSZ;
      short4v pk;
#pragma unroll
      for (int j = 0; j < 4; ++j) {
        const float* xc = xb + j * HWSZ;
        float v = wt.x * xc[i00] + wt.y * xc[i01] + wt.z * xc[i10] + wt.w * xc[i11];
        pk[j] = (short)f2bf(v);
      }
      *(short4v*)&A_lds[m * 40 + cg * 4] = pk;
    }
    {
      const short8* bp = (const short8*)(Bw + tid * KTOT + (t << 8) + c0);
      short8 b0 = bp[0], b1 = bp[1], b2 = bp[2], b3 = bp[3];
      short8* dst = (short8*)&B_lds[tid * 40];
      dst[0] = b0; dst[1] = b1; dst[2] = b2; dst[3] = b3;
    }
    __syncthreads();
    int fr = (lane >> 4) * 8;
    short8 a0 = *(short8*)&A_lds[((lane & 15)) * 40 + fr];
    short8 a1 = *(short8*)&A_lds[(16 + (lane & 15)) * 40 + fr];
#pragma unroll
    for (int nj = 0; nj < 4; ++nj) {
      short8 bfp = *(short8*)&B_lds[(n0 + nj * 16 + (lane & 15)) * 40 + fr];
      acc[0][nj] = __builtin_amdgcn_mfma_f32_16x16x32_bf16(a0, bfp, acc[0][nj], 0, 0, 0);
      acc[1][nj] = __builtin_amdgcn_mfma_f32_16x16x32_bf16(a1, bfp, acc[1][nj], 0, 0, 0);
    }
  }
  int g = lane >> 4;
#pragma unroll
  for (int mi = 0; mi < 2; ++mi) {
    int wm = w0 + mi * 16 + g * 4;
#pragma unroll
    for (int nj = 0; nj < 4; ++nj) {
      int oc = n0 + nj * 16 + (lane & 15);
      float4 vv = make_float4(acc[mi][nj][0], acc[mi][nj][1],
                              acc[mi][nj][2], acc[mi][nj][3]);
      *(float4*)&out[((n * OUTC + oc) << 12) + h * 64 + wm] = vv;
    }
  }
}

// ---------------------------------------------------------------------------
extern "C" void kernel_launch(void* const* d_in, const int* in_sizes, int n_in,
                              void* d_out, int out_size, void* d_ws, size_t ws_size,
                              hipStream_t stream) {
  const float* x     = (const float*)d_in[0];
  const float* offw  = (const float*)d_in[1];
  const float* ob    = (const float*)d_in[2];
  const float* dcn_w = (const float*)d_in[3];
  float* out = (float*)d_out;

  unsigned short* Bw  = (unsigned short*)((char*)d_ws + WS_BW_OFF);
  unsigned short* B2w = (unsigned short*)((char*)d_ws + WS_B2W_OFF);
  float*          omb = (float*)((char*)d_ws + WS_OM_OFF);
  unsigned short* xtb = (unsigned short*)((char*)d_ws + WS_XT_OFF);
  unsigned short* Abuf = (unsigned short*)((char*)d_ws + WS_A_OFF);

  const size_t perimg = (size_t)HWSZ * KTOT * 2;   // 18.87 MB per image of A
  const size_t head   = (size_t)WS_A_OFF;          // ~11.5 MB

  int imgs_per_chunk = 0;
  if (ws_size >= head + 4 * perimg)      imgs_per_chunk = 4;
  else if (ws_size >= head + 2 * perimg) imgs_per_chunk = 2;
  else if (ws_size >= head + 1 * perimg) imgs_per_chunk = 1;

  prep_kernel<<<256, 256, 0, stream>>>(dcn_w, offw, Bw, B2w);

  if (imgs_per_chunk > 0) {
    xpose_kernel<<<256, 256, 0, stream>>>(x, xtb);
    conv_offset_stream<<<MTOT / 32, 256, 0, stream>>>(xtb, B2w, omb);
    for (int i0 = 0; i0 < NB; i0 += imgs_per_chunk) {
      int ni = imgs_per_chunk;
      if (i0 + ni > NB) ni = NB - i0;
      sample_kernel<<<ni * 128, 256, 0, stream>>>(xtb, omb, ob, Abuf, i0);
      gemm_kernel<<<(ni * HWSZ / 64) * 2, 256, 0, stream>>>(
          Abuf, Bw, out + (size_t)i0 * OUTC * HWSZ);
    }
  } else {
    conv_offset_kernel<<<NB * HH, 256, 0, stream>>>(x, B2w, ob, omb);
    dcn_main_kernel<<<NB * HH * 2, 256, 0, stream>>>(x, omb, Bw, out);
  }
}

// Round 5
// 161.994 us; speedup vs baseline: 6.3625x; 1.1157x over previous
//
#include <hip/hip_runtime.h>
#include <hip/hip_bf16.h>
#include <math.h>

// Problem constants (N, C, H, W) = (4, 256, 64, 64), out_C = 256, FS=3, pad=1, stride=1
#define NB     4
#define CIN    256
#define HH     64
#define WW     64
#define OUTC   256
#define K2     9
#define KTOT   2304                // CIN * K2
#define HWSZ   4096                // HH * WW
#define NSTEPS 72                  // KTOT / 32
#define MTOT   16384               // NB * HWSZ

// K ordering everywhere: k' = tap*256 + c (tap-major).

typedef __attribute__((ext_vector_type(4))) float  floatx4;
typedef __attribute__((ext_vector_type(8))) short  short8;
typedef __attribute__((ext_vector_type(4))) short  short4v;
typedef __attribute__((ext_vector_type(4))) int    intx4;

__device__ __forceinline__ unsigned short f2bf(float f) {
  union { float f; unsigned u; } v; v.f = f;
  unsigned r = v.u + 0x7FFF + ((v.u >> 16) & 1);   // round-to-nearest-even
  return (unsigned short)(r >> 16);
}
__device__ __forceinline__ float b2f(unsigned short s) {
  union { unsigned u; float f; } v; v.u = ((unsigned)s) << 16;
  return v.f;
}

__device__ __forceinline__ void load_lds16(const void* g, void* l) {
  __builtin_amdgcn_global_load_lds(
      (const __attribute__((address_space(1))) unsigned int*)g,
      (__attribute__((address_space(3))) unsigned int*)l, 16, 0, 0);
}

// Workspace layout (bytes):
//   Bw  : [256 oc][2304 k'] bf16 = 1,179,648
//   B2w : [32 oc ][2304 k'] bf16 =   147,456
//   om  : [4][27][64][64] fp32   = 1,769,472   (RAW conv out, no bias/sigmoid)
//   xt  : [4][64][64][256] bf16  = 8,388,608   (channel-last transposed x)
#define WS_BW_OFF   0
#define WS_B2W_OFF  (KTOT * OUTC * 2)
#define WS_OM_OFF   (WS_B2W_OFF + KTOT * 32 * 2)
#define WS_XT_OFF   (WS_OM_OFF + NB * 27 * HWSZ * 4)
#define WS_END      (WS_XT_OFF + NB * HWSZ * CIN * 2)

// ---------------------------------------------------------------------------
// Kernel 0: fused weight-prep (blocks 0..255) + x transpose (blocks 256..511).
//   prep : Bw/B2w bf16, k' = t*256 + c ordering.
//   xpose: x [img][c][h][w] fp32 -> xt [img][h][w][c] bf16 via LDS tile.
// ---------------------------------------------------------------------------
__global__ __launch_bounds__(256) void prep_xpose_kernel(
    const float* __restrict__ dcn_w, const float* __restrict__ offw,
    const float* __restrict__ x,
    unsigned short* __restrict__ Bw, unsigned short* __restrict__ B2w,
    unsigned short* __restrict__ xt) {
  int bid = blockIdx.x;
  if (bid < 256) {
    int oc = bid;
    for (int k = threadIdx.x; k < KTOT; k += 256) {
      int t = k >> 8, c = k & 255;
      Bw[oc * KTOT + k] = f2bf(dcn_w[oc * KTOT + c * 9 + t]);
      if (oc < 32)
        B2w[oc * KTOT + k] = (oc < 27) ? f2bf(offw[oc * KTOT + c * 9 + t])
                                       : (unsigned short)0;
    }
  } else {
    __shared__ unsigned short T[64 * 266];   // [w][c], pad 266
    int b2 = bid - 256;
    int img = b2 >> 6, h = b2 & 63;
    const float* xp = x + (size_t)img * CIN * HWSZ + h * 64;
    int tid = threadIdx.x;
    int w = tid & 63, cq = tid >> 6;
    for (int cb = 0; cb < 256; cb += 4) {
      int c = cb + cq;
      T[w * 266 + c] = f2bf(xp[(size_t)c * HWSZ + w]);   // lanes=w: coalesced
    }
    __syncthreads();
    int w2 = tid >> 2, cg = (tid & 3) << 6;
    unsigned short* o = xt + ((size_t)(img * 64 + h) * 64 + w2) * 256 + cg;
#pragma unroll
    for (int i = 0; i < 64; i += 8) {
      short8 v = *(short8*)&T[w2 * 266 + cg + i];
      *(short8*)(o + i) = v;
    }
  }
}

// ---------------------------------------------------------------------------
// Kernel 1: offset conv, streaming register-fragment MFMA (no LDS, no barrier).
// Grid = MTOT/32 = 512 blocks, 256 thr. A-fragments are single 16B loads
// from channel-last xt. Writes RAW om.
// ---------------------------------------------------------------------------
__global__ __launch_bounds__(256) void conv_offset_stream(
    const unsigned short* __restrict__ xt, const unsigned short* __restrict__ B2w,
    float* __restrict__ om) {
  int tid = threadIdx.x, lane = tid & 63, q = tid >> 6;
  int qm = q & 1, qn = q >> 1;
  int quad = lane >> 4, l15 = lane & 15;
  int mbase = blockIdx.x * 32 + qm * 16;
  int mrow  = mbase + l15;
  int w = mrow & 63, h = (mrow >> 6) & 63, img = mrow >> 12;
  const unsigned short* xn = xt + (size_t)img * HWSZ * 256;
  int ocr = qn * 16 + l15;
  const unsigned short* bbase = B2w + ocr * KTOT + quad * 8;

  floatx4 acc = {0.f, 0.f, 0.f, 0.f};
  for (int s = 0; s < NSTEPS; ++s) {
    int t  = s >> 3;
    int cb = ((s & 7) << 5) + (quad << 3);
    int dy = t / 3 - 1, dx = t % 3 - 1;
    int y = h + dy, xx = w + dx;
    bool inb = ((unsigned)y < 64u) && ((unsigned)xx < 64u);
    short8 af = {0, 0, 0, 0, 0, 0, 0, 0};
    if (inb) af = *(const short8*)(xn + ((size_t)(y * 64 + xx)) * 256 + cb);
    short8 bf = *(const short8*)(bbase + s * 32);
    acc = __builtin_amdgcn_mfma_f32_16x16x32_bf16(af, bf, acc, 0, 0, 0);
  }
  if (ocr < 27) {
    int m0 = mbase + quad * 4;
    int img2 = m0 >> 12, hw = m0 & 4095;
    float4 vv = make_float4(acc[0], acc[1], acc[2], acc[3]);
    *(float4*)&om[(img2 * 27 + ocr) * HWSZ + hw] = vv;
  }
}

// ---------------------------------------------------------------------------
// Kernel 2: FUSED deformable sampling + main GEMM.
// Block: M=64 (one (img,h) row), N=256 (all oc), K=2304 (9 taps x 4 chunks).
// Grid 256 blocks x 512 thr (8 waves, 2/SIMD). Wave q: qm=q&1 (32 m),
// qn=q>>1 (64 oc) -> 2m x 4n 16x16 tiles, 16 MFMA/step.
// Per step each thread: sample 1m x 8c (4 coalesced 16B corner loads from
// channel-last xt) -> swizzled ds_write_b128; B via 4x load_lds16 (w=16).
// ---------------------------------------------------------------------------
__global__ __launch_bounds__(512, 2) void dcn_fused_kernel(
    const unsigned short* __restrict__ xt, const float* __restrict__ om,
    const float* __restrict__ ob, const unsigned short* __restrict__ Bw,
    float* __restrict__ out) {
  __shared__ unsigned short Ald[64 * 64];     //  8 KB
  __shared__ unsigned short Bld[256 * 64];    // 32 KB
  __shared__ intx4  sOff[576];                //  9 KB  (corner short-offsets)
  __shared__ float4 sWt[576];                 //  9 KB  (mask-premult weights)

  int bid = blockIdx.x;                 // 0..255
  int img = bid >> 6, h = bid & 63;
  int M0  = bid * 64;
  const unsigned short* xb = xt + (size_t)img * HWSZ * 256;
  const float* omn = om + img * (27 * HWSZ);

  int tid  = threadIdx.x;
  int lane = tid & 63, q = tid >> 6;    // q 0..7
  int qm = q & 1, qn = q >> 1;          // qn 0..3
  int quad = lane >> 4, l15 = lane & 15;

  // ---- bilinear params: 9 taps x 64 w ----
  for (int v = tid; v < 576; v += 512) {
    int w = v & 63, t = v >> 6;
    int ky = t / 3, kx = t % 3;
    int sp = h * 64 + w;
    float offy = omn[(2 * t) * HWSZ + sp] + ob[2 * t];
    float offx = omn[(2 * t + 1) * HWSZ + sp] + ob[2 * t + 1];
    float mraw = omn[(18 + t) * HWSZ + sp] + ob[18 + t];
    float mv   = 1.0f / (1.0f + __expf(-mraw));
    float him  = (float)(h - 1 + ky) + offy;
    float wim  = (float)(w - 1 + kx) + offx;
    float y0f = floorf(him), x0f = floorf(wim);
    float lh = him - y0f, lw = wim - x0f;
    int y0 = (int)y0f, x0i = (int)x0f;
    bool vy0 = (y0 >= 0) && (y0 < HH);
    bool vy1 = (y0 + 1 >= 0) && (y0 + 1 < HH);
    bool vx0 = (x0i >= 0) && (x0i < WW);
    bool vx1 = (x0i + 1 >= 0) && (x0i + 1 < WW);
    float hh_ = 1.0f - lh, hw_ = 1.0f - lw;
    float4 wt;
    wt.x = (vy0 && vx0) ? hh_ * hw_ * mv : 0.0f;
    wt.y = (vy0 && vx1) ? hh_ * lw  * mv : 0.0f;
    wt.z = (vy1 && vx0) ? lh  * hw_ * mv : 0.0f;
    wt.w = (vy1 && vx1) ? lh  * lw  * mv : 0.0f;
    int y0c = min(max(y0, 0), 63), y1c = min(max(y0 + 1, 0), 63);
    int x0c = min(max(x0i, 0), 63), x1c = min(max(x0i + 1, 0), 63);
    intx4 ii = {(y0c * 64 + x0c) << 8, (y0c * 64 + x1c) << 8,
                (y1c * 64 + x0c) << 8, (y1c * 64 + x1c) << 8};
    sOff[v] = ii;
    sWt[v]  = wt;
  }

  floatx4 acc[2][4];
#pragma unroll
  for (int mi = 0; mi < 2; ++mi)
#pragma unroll
    for (int nj = 0; nj < 4; ++nj) acc[mi][nj] = (floatx4){0.f, 0.f, 0.f, 0.f};

  int sm = tid >> 3, scg = tid & 7;     // A-sample: m row, 8-c chunk
  int srow = lane >> 3, schk = lane & 7; // B-stage lane split

  __syncthreads();                      // params ready

  for (int t = 0; t < 9; ++t) {
    intx4  off = sOff[t * 64 + sm];     // per-thread corner offsets (shorts)
    float4 wt  = sWt[t * 64 + sm];
    const int tk = t << 8;
#pragma unroll
    for (int cc = 0; cc < 4; ++cc) {
      int c0 = cc << 6;
      __syncthreads();                  // protect previous step's frag reads
      // ---- A: sample 1m x 8c, swizzled ds_write_b128 ----
      {
        int cbeg = c0 + (scg << 3);
        short8 v0 = *(const short8*)(xb + off.x + cbeg);
        short8 v1 = *(const short8*)(xb + off.y + cbeg);
        short8 v2 = *(const short8*)(xb + off.z + cbeg);
        short8 v3 = *(const short8*)(xb + off.w + cbeg);
        short8 pk;
#pragma unroll
        for (int j = 0; j < 8; ++j) {
          float v = wt.x * b2f((unsigned short)v0[j]) +
                    wt.y * b2f((unsigned short)v1[j]) +
                    wt.z * b2f((unsigned short)v2[j]) +
                    wt.w * b2f((unsigned short)v3[j]);
          pk[j] = (short)f2bf(v);
        }
        *(short8*)&Ald[sm * 64 + ((scg ^ (sm & 7)) << 3)] = pk;
      }
      // ---- B: 256 rows x 64 c via load_lds16, XOR-chunk swizzle ----
#pragma unroll
      for (int it = 0; it < 4; ++it) {
        int rb = q * 32 + it * 8;
        int r  = rb + srow;
        const unsigned short* g =
            Bw + (size_t)r * KTOT + tk + c0 + ((schk ^ (r & 7)) << 3);
        load_lds16(g, &Bld[rb * 64]);
      }
      __syncthreads();
      // ---- 16 MFMA ----
#pragma unroll
      for (int ks = 0; ks < 2; ++ks) {
        int cbase = ks * 4 + quad;
        short8 a[2], b[4];
#pragma unroll
        for (int mi = 0; mi < 2; ++mi) {
          int r = qm * 32 + mi * 16 + l15;
          a[mi] = *(short8*)&Ald[r * 64 + ((cbase ^ (r & 7)) << 3)];
        }
#pragma unroll
        for (int nj = 0; nj < 4; ++nj) {
          int r = qn * 64 + nj * 16 + l15;
          b[nj] = *(short8*)&Bld[r * 64 + ((cbase ^ (r & 7)) << 3)];
        }
#pragma unroll
        for (int mi = 0; mi < 2; ++mi)
#pragma unroll
          for (int nj = 0; nj < 4; ++nj)
            acc[mi][nj] = __builtin_amdgcn_mfma_f32_16x16x32_bf16(
                a[mi], b[nj], acc[mi][nj], 0, 0, 0);
      }
    }
  }

  // ---- epilogue ----
#pragma unroll
  for (int mi = 0; mi < 2; ++mi) {
    int m0 = M0 + qm * 32 + mi * 16 + quad * 4;
    int img2 = m0 >> 12, hw = m0 & 4095;
#pragma unroll
    for (int nj = 0; nj < 4; ++nj) {
      int oc = qn * 64 + nj * 16 + l15;
      float4 vv = make_float4(acc[mi][nj][0], acc[mi][nj][1],
                              acc[mi][nj][2], acc[mi][nj][3]);
      *(float4*)&out[((size_t)img2 * OUTC + oc) * HWSZ + hw] = vv;
    }
  }
}

// ===========================================================================
// FALLBACK PATH (round-2 fused kernels) — only if ws is too small.
// ===========================================================================
__global__ __launch_bounds__(256) void conv_offset_kernel(
    const float* __restrict__ x, const unsigned short* __restrict__ B2w,
    const float* __restrict__ ob, float* __restrict__ om) {
  __shared__ unsigned short A_lds[64 * 40];
  __shared__ unsigned short B_lds[32 * 40];
  int bid = blockIdx.x;
  int n = bid >> 6, h = bid & 63;
  int tid = threadIdx.x, lane = tid & 63, q = tid >> 6;
  const float* xn = x + n * (CIN * HWSZ);
  floatx4 acc0 = {0.f, 0.f, 0.f, 0.f}, acc1 = {0.f, 0.f, 0.f, 0.f};
  int w = tid & 63, cg = tid >> 6, ocb = tid >> 3, part = tid & 7;
  for (int s = 0; s < NSTEPS; ++s) {
    int t = s >> 3, c0 = (s & 7) << 5;
    int dy = t / 3 - 1, dx = t % 3 - 1;
    __syncthreads();
    {
      int y = h + dy, xx = w + dx;
      bool inb = ((unsigned)y < 64u) && ((unsigned)xx < 64u);
      const float* xb = xn + (c0 + cg * 8) * HWSZ + y * 64 + xx;
      short8 pk;
#pragma unroll
      for (int j = 0; j < 8; ++j) { float v = inb ? xb[j * HWSZ] : 0.0f; pk[j] = (short)f2bf(v); }
      *(short8*)&A_lds[w * 40 + cg * 8] = pk;
    }
    { const unsigned short* bp = B2w + ocb * KTOT + (t << 8) + c0 + part * 4;
      *(short4v*)&B_lds[ocb * 40 + part * 4] = *(const short4v*)bp; }
    __syncthreads();
    int fr = (lane >> 4) * 8;
    short8 af  = *(short8*)&A_lds[(q * 16 + (lane & 15)) * 40 + fr];
    short8 bf0 = *(short8*)&B_lds[((lane & 15)) * 40 + fr];
    short8 bf1 = *(short8*)&B_lds[(16 + (lane & 15)) * 40 + fr];
    acc0 = __builtin_amdgcn_mfma_f32_16x16x32_bf16(af, bf0, acc0, 0, 0, 0);
    acc1 = __builtin_amdgcn_mfma_f32_16x16x32_bf16(af, bf1, acc1, 0, 0, 0);
  }
  int g = lane >> 4;
#pragma unroll
  for (int nt = 0; nt < 2; ++nt) {
    floatx4 a = nt ? acc1 : acc0;
    int oc = nt * 16 + (lane & 15);
    if (oc < 27) {
      float bias = ob[oc];
#pragma unroll
      for (int r = 0; r < 4; ++r) {
        int wm = q * 16 + g * 4 + r;
        float val = a[r] + bias;
        if (oc >= 18) val = 1.0f / (1.0f + __expf(-val));
        om[((n * 27 + oc) << 12) + h * 64 + wm] = val;
      }
    }
  }
}

__global__ __launch_bounds__(256) void dcn_main_kernel(
    const float* __restrict__ x, const float* __restrict__ om,
    const unsigned short* __restrict__ Bw, float* __restrict__ out) {
  __shared__ unsigned short A_lds[32 * 40];
  __shared__ unsigned short B_lds[256 * 40];
  __shared__ int    sY[288];
  __shared__ int    sX[288];
  __shared__ float4 sW[288];
  int bid = blockIdx.x;
  int n = bid >> 7, rem = bid & 127, h = rem >> 1, w0 = (rem & 1) << 5;
  int tid = threadIdx.x, lane = tid & 63, q = tid >> 6;
  const float* xn  = x + n * (CIN * HWSZ);
  const float* omn = om + n * (27 * HWSZ);
  for (int v = tid; v < 288; v += 256) {
    int m = v & 31, t = v >> 5;
    int ky = t / 3, kx = t % 3;
    int wg = w0 + m, sp = h * 64 + wg;
    float offy = omn[(2 * t) * HWSZ + sp];
    float offx = omn[(2 * t + 1) * HWSZ + sp];
    float mv   = omn[(18 + t) * HWSZ + sp];
    float him = (float)(h - 1 + ky) + offy;
    float wim = (float)(wg - 1 + kx) + offx;
    float y0f = floorf(him), x0f = floorf(wim);
    float lh = him - y0f, lw = wim - x0f;
    int y0 = (int)y0f, x0i = (int)x0f;
    bool vy0 = (y0 >= 0) && (y0 < HH), vy1 = (y0 + 1 >= 0) && (y0 + 1 < HH);
    bool vx0 = (x0i >= 0) && (x0i < WW), vx1 = (x0i + 1 >= 0) && (x0i + 1 < WW);
    float hh_ = 1.0f - lh, hw_ = 1.0f - lw;
    float4 wt;
    wt.x = (vy0 && vx0) ? hh_ * hw_ * mv : 0.0f;
    wt.y = (vy0 && vx1) ? hh_ * lw  * mv : 0.0f;
    wt.z = (vy1 && vx0) ? lh  * hw_ * mv : 0.0f;
    wt.w = (vy1 && vx1) ? lh  * lw  * mv : 0.0f;
    sY[v] = y0; sX[v] = x0i; sW[v] = wt;
  }
  floatx4 acc[2][4];
#pragma unroll
  for (int mi = 0; mi < 2; ++mi)
#pragma unroll
    for (int nj = 0; nj < 4; ++nj) acc[mi][nj] = (floatx4){0.f, 0.f, 0.f, 0.f};
  int m = tid & 31, cg = tid >> 5, n0 = q * 64;
  for (int s = 0; s < NSTEPS; ++s) {
    int t = s >> 3, c0 = (s & 7) << 5;
    __syncthreads();
    {
      int p = t * 32 + m;
      int y0 = sY[p], x0i = sX[p];
      float4 wt = sW[p];
      int y0c = min(max(y0, 0), 63), y1c = min(max(y0 + 1, 0), 63);
      int x0c = min(max(x0i, 0), 63), x1c = min(max(x0i + 1, 0), 63);
      int i00 = y0c * 64 + x0c, i01 = y0c * 64 + x1c;
      int i10 = y1c * 64 + x0c, i11 = y1c * 64 + x1c;
      const float* xb = xn + (c0 + cg * 4) * HWSZ;
      short4v pk;
#pragma unroll
      for (int j = 0; j < 4; ++j) {
        const float* xc = xb + j * HWSZ;
        float v = wt.x * xc[i00] + wt.y * xc[i01] + wt.z * xc[i10] + wt.w * xc[i11];
        pk[j] = (short)f2bf(v);
      }
      *(short4v*)&A_lds[m * 40 + cg * 4] = pk;
    }
    {
      const short8* bp = (const short8*)(Bw + tid * KTOT + (t << 8) + c0);
      short8 b0 = bp[0], b1 = bp[1], b2 = bp[2], b3 = bp[3];
      short8* dst = (short8*)&B_lds[tid * 40];
      dst[0] = b0; dst[1] = b1; dst[2] = b2; dst[3] = b3;
    }
    __syncthreads();
    int fr = (lane >> 4) * 8;
    short8 a0 = *(short8*)&A_lds[((lane & 15)) * 40 + fr];
    short8 a1 = *(short8*)&A_lds[(16 + (lane & 15)) * 40 + fr];
#pragma unroll
    for (int nj = 0; nj < 4; ++nj) {
      short8 bfp = *(short8*)&B_lds[(n0 + nj * 16 + (lane & 15)) * 40 + fr];
      acc[0][nj] = __builtin_amdgcn_mfma_f32_16x16x32_bf16(a0, bfp, acc[0][nj], 0, 0, 0);
      acc[1][nj] = __builtin_amdgcn_mfma_f32_16x16x32_bf16(a1, bfp, acc[1][nj], 0, 0, 0);
    }
  }
  int g = lane >> 4;
#pragma unroll
  for (int mi = 0; mi < 2; ++mi) {
    int wm = w0 + mi * 16 + g * 4;
#pragma unroll
    for (int nj = 0; nj < 4; ++nj) {
      int oc = n0 + nj * 16 + (lane & 15);
      float4 vv = make_float4(acc[mi][nj][0], acc[mi][nj][1],
                              acc[mi][nj][2], acc[mi][nj][3]);
      *(float4*)&out[((n * OUTC + oc) << 12) + h * 64 + wm] = vv;
    }
  }
}

// ---------------------------------------------------------------------------
extern "C" void kernel_launch(void* const* d_in, const int* in_sizes, int n_in,
                              void* d_out, int out_size, void* d_ws, size_t ws_size,
                              hipStream_t stream) {
  const float* x     = (const float*)d_in[0];
  const float* offw  = (const float*)d_in[1];
  const float* ob    = (const float*)d_in[2];
  const float* dcn_w = (const float*)d_in[3];
  float* out = (float*)d_out;

  unsigned short* Bw  = (unsigned short*)((char*)d_ws + WS_BW_OFF);
  unsigned short* B2w = (unsigned short*)((char*)d_ws + WS_B2W_OFF);
  float*          omb = (float*)((char*)d_ws + WS_OM_OFF);
  unsigned short* xtb = (unsigned short*)((char*)d_ws + WS_XT_OFF);

  if (ws_size >= (size_t)WS_END) {
    // main path: 3 launches, no A materialization
    prep_xpose_kernel<<<512, 256, 0, stream>>>(dcn_w, offw, x, Bw, B2w, xtb);
    conv_offset_stream<<<MTOT / 32, 256, 0, stream>>>(xtb, B2w, omb);
    dcn_fused_kernel<<<256, 512, 0, stream>>>(xtb, omb, ob, Bw, out);
  } else {
    // fallback: round-2 fused kernels (needs only ~3.1 MB of ws)
    prep_xpose_kernel<<<256, 256, 0, stream>>>(dcn_w, offw, x, Bw, B2w, xtb);
    conv_offset_kernel<<<NB * HH, 256, 0, stream>>>(x, B2w, ob, omb);
    dcn_main_kernel<<<NB * HH * 2, 256, 0, stream>>>(x, omb, Bw, out);
  }
}